// Round 2
// baseline (3959.556 us; speedup 1.0000x reference)
//
#include <hip/hip_runtime.h>
#include <hip/hip_bf16.h>

typedef __hip_bfloat16 bf16;
typedef __attribute__((ext_vector_type(8))) short bfrag8;
typedef __attribute__((ext_vector_type(4))) float facc4;

#define NQ_ 100000
#define NP_ 200000
#define NE_ 500000

static __device__ __forceinline__ short f2bf_bits(float f) {
    bf16 h = __float2bfloat16(f);
    short r;
    __builtin_memcpy(&r, &h, 2);
    return r;
}

static __device__ __forceinline__ void store_val(bf16* p, float v) { *p = __float2bfloat16(v); }
static __device__ __forceinline__ void store_val(float* p, float v) { *p = v; }

// fp32 -> bf16 cast, 4 elems/thread
__global__ void cast_to_bf16(const float* __restrict__ x, bf16* __restrict__ y, int n4) {
    int i = blockIdx.x * blockDim.x + threadIdx.x;
    if (i >= n4) return;
    float4 v = reinterpret_cast<const float4*>(x)[i];
    short4 o;
    o.x = f2bf_bits(v.x);
    o.y = f2bf_bits(v.y);
    o.z = f2bf_bits(v.z);
    o.w = f2bf_bits(v.w);
    reinterpret_cast<short4*>(y)[i] = o;
}

// Combine + transpose weights (fp32 in, bf16 out): Wt[m][n*128+k], m = (l*2+t)*3+s
// t=0 (P-dst): relations (0=click, 3=qres); t=1 (Q-dst): relations (1=rclick, 2=rqres)
// s=0: Wself[rA]+Wself[rB]; s=1: Wneigh[rA]; s=2: Wneigh[rB]
__global__ void prep_weights(const float* __restrict__ Wself, const float* __restrict__ Wneigh,
                             bf16* __restrict__ Wt) {
    int g = blockIdx.x * blockDim.x + threadIdx.x;
    if (g >= 12 * 16384) return;
    int m = g >> 14;
    int rem = g & 16383;
    int n = rem >> 7, k = rem & 127;
    int l = m / 6, t = (m / 3) % 2, s = m % 3;
    int rA = (t == 0) ? 0 : 1;
    int rB = (t == 0) ? 3 : 2;
    float v;
    if (s == 0) {
        v = Wself[((size_t)(l * 4 + rA) * 128 + k) * 128 + n]
          + Wself[((size_t)(l * 4 + rB) * 128 + k) * 128 + n];
    } else {
        int r = (s == 1) ? rA : rB;
        v = Wneigh[((size_t)(l * 4 + r) * 128 + k) * 128 + n];
    }
    Wt[(size_t)m * 16384 + n * 128 + k] = __float2bfloat16(v);
}

// bsum[l][t][n] = bias[l][rA][n] + bias[l][rB][n]  (fp32)
__global__ void prep_bias(const float* __restrict__ bias, float* __restrict__ bsum) {
    int g = blockIdx.x * blockDim.x + threadIdx.x;
    if (g >= 512) return;
    int l = g >> 8, t = (g >> 7) & 1, n = g & 127;
    int rA = (t == 0) ? 0 : 1;
    int rB = (t == 0) ? 3 : 2;
    bsum[g] = bias[(l * 4 + rA) * 128 + n] + bias[(l * 4 + rB) * 128 + n];
}

// one thread per edge: count in-degree (graph is layer-invariant; run once)
__global__ void deg_count(const int* __restrict__ dst, float* __restrict__ deg, int nE) {
    int e = blockIdx.x * blockDim.x + threadIdx.x;
    if (e < nE) unsafeAtomicAdd(deg + dst[e], 1.0f);
}

// One wave per edge: lane i handles features 2i, 2i+1 (bf16 source rows, fp32 atomic sums)
__global__ void scatter_add(const bf16* __restrict__ h, const int* __restrict__ src,
                            const int* __restrict__ dst, float* __restrict__ msum, int nE) {
    int e = blockIdx.x * 4 + (threadIdx.x >> 6);
    if (e >= nE) return;
    int lane = threadIdx.x & 63;
    int s = src[e], d = dst[e];
    const __hip_bfloat162* hp = reinterpret_cast<const __hip_bfloat162*>(h + (size_t)s * 128);
    __hip_bfloat162 v = hp[lane];
    float* o = msum + (size_t)d * 128 + lane * 2;
    unsafeAtomicAdd(o, __low2float(v));
    unsafeAtomicAdd(o + 1, __high2float(v));
}

// out[i,:] = act( hdst[i,:]@W0 + mean1[i,:]@W1 + mean2[i,:]@W2 + bias )
// Wt3: 3 matrices, each stored transposed [n][k], 128x128 bf16
template <typename OT>
__global__ __launch_bounds__(256, 2)
void sage_update(const bf16* __restrict__ hdst,
                 const float* __restrict__ msum1, const float* __restrict__ deg1,
                 const float* __restrict__ msum2, const float* __restrict__ deg2,
                 const bf16* __restrict__ Wt3, const float* __restrict__ bsum,
                 OT* __restrict__ out, int nrows, int do_relu) {
    __shared__ short lA[64 * 136];   // A tile, stride 136 (272B: 16B-aligned, conflict-free for b128)
    __shared__ short lW[128 * 136];  // W^T tile
    const int tid = threadIdx.x;
    const int wave = tid >> 6, lane = tid & 63;
    const int i16 = lane & 15, quad = lane >> 4;
    const int row0 = blockIdx.x * 64;

    facc4 acc[4][2];
    for (int nt = 0; nt < 2; ++nt) {
        float bv = bsum[wave * 32 + nt * 16 + i16];
        for (int mt = 0; mt < 4; ++mt) {
            facc4 a = {bv, bv, bv, bv};
            acc[mt][nt] = a;
        }
    }

    for (int s = 0; s < 3; ++s) {
        __syncthreads();
        // stage W_s^T (coalesced 16B copies)
        {
            const int4* srcw = reinterpret_cast<const int4*>(Wt3 + (size_t)s * 16384);
            for (int j = 0; j < 8; ++j) {
                int c = j * 256 + tid;        // chunk of 8 bf16
                int n = c >> 4, k = (c & 15) * 8;
                int4 v = srcw[c];
                *reinterpret_cast<int4*>(&lW[n * 136 + k]) = v;
            }
        }
        // stage A_s
        if (s == 0) {
            for (int j = 0; j < 4; ++j) {
                int c = j * 256 + tid;
                int r = c >> 4, k = (c & 15) * 8;
                int grow = row0 + r;
                int4 v = {0, 0, 0, 0};
                if (grow < nrows)
                    v = reinterpret_cast<const int4*>(hdst)[((size_t)grow * 128 + k) >> 3];
                *reinterpret_cast<int4*>(&lA[r * 136 + k]) = v;
            }
        } else {
            const float* msum = (s == 1) ? msum1 : msum2;
            const float* dg   = (s == 1) ? deg1 : deg2;
            for (int j = 0; j < 4; ++j) {
                int c = j * 256 + tid;
                int r = c >> 4, k = (c & 15) * 8;
                int grow = row0 + r;
                alignas(16) short tmp[8] = {0, 0, 0, 0, 0, 0, 0, 0};
                if (grow < nrows) {
                    float rdeg = 1.0f / fmaxf(dg[grow], 1.0f);
                    const float4* mp = reinterpret_cast<const float4*>(msum + (size_t)grow * 128 + k);
                    float4 f0 = mp[0], f1 = mp[1];
                    tmp[0] = f2bf_bits(f0.x * rdeg);
                    tmp[1] = f2bf_bits(f0.y * rdeg);
                    tmp[2] = f2bf_bits(f0.z * rdeg);
                    tmp[3] = f2bf_bits(f0.w * rdeg);
                    tmp[4] = f2bf_bits(f1.x * rdeg);
                    tmp[5] = f2bf_bits(f1.y * rdeg);
                    tmp[6] = f2bf_bits(f1.z * rdeg);
                    tmp[7] = f2bf_bits(f1.w * rdeg);
                }
                *reinterpret_cast<int4*>(&lA[r * 136 + k]) = *reinterpret_cast<int4*>(tmp);
            }
        }
        __syncthreads();
        // K loop: 4 x (K=32) MFMA steps
        for (int k0 = 0; k0 < 128; k0 += 32) {
            bfrag8 a[4], b[2];
            for (int mt = 0; mt < 4; ++mt)
                a[mt] = *reinterpret_cast<const bfrag8*>(&lA[(mt * 16 + i16) * 136 + k0 + quad * 8]);
            for (int nt = 0; nt < 2; ++nt)
                b[nt] = *reinterpret_cast<const bfrag8*>(&lW[(wave * 32 + nt * 16 + i16) * 136 + k0 + quad * 8]);
            for (int mt = 0; mt < 4; ++mt)
                for (int nt = 0; nt < 2; ++nt)
                    acc[mt][nt] = __builtin_amdgcn_mfma_f32_16x16x32_bf16(a[mt], b[nt], acc[mt][nt], 0, 0, 0);
        }
    }

    // epilogue: D[m][n], m = quad*4+r (within 16-tile), n = i16
    for (int mt = 0; mt < 4; ++mt) {
        for (int nt = 0; nt < 2; ++nt) {
            int n = wave * 32 + nt * 16 + i16;
            for (int r = 0; r < 4; ++r) {
                int m = mt * 16 + quad * 4 + r;
                int grow = row0 + m;
                if (grow < nrows) {
                    float v = acc[mt][nt][r];
                    if (do_relu) v = fmaxf(v, 0.0f);
                    store_val(out + (size_t)grow * 128 + n, v);
                }
            }
        }
    }
}

extern "C" void kernel_launch(void* const* d_in, const int* in_sizes, int n_in,
                              void* d_out, int out_size, void* d_ws, size_t ws_size,
                              hipStream_t stream) {
    const float* xq     = (const float*)d_in[0];
    const float* xp     = (const float*)d_in[1];
    const float* Wself  = (const float*)d_in[2];
    const float* Wneigh = (const float*)d_in[3];
    const float* bias   = (const float*)d_in[4];
    const int* csrc  = (const int*)d_in[5];
    const int* cdst  = (const int*)d_in[6];
    const int* qsrc  = (const int*)d_in[7];
    const int* qdst  = (const int*)d_in[8];
    const int* rcsrc = (const int*)d_in[9];
    const int* rcdst = (const int*)d_in[10];
    const int* rqsrc = (const int*)d_in[11];
    const int* rqdst = (const int*)d_in[12];

    char* w = (char*)d_ws;
    bf16* xqb    = (bf16*)w;  w += (size_t)NQ_ * 128 * 2;
    bf16* xpb    = (bf16*)w;  w += (size_t)NP_ * 128 * 2;
    bf16* hQ1    = (bf16*)w;  w += (size_t)NQ_ * 128 * 2;
    bf16* hP1    = (bf16*)w;  w += (size_t)NP_ * 128 * 2;
    float* msumA = (float*)w; w += (size_t)NP_ * 128 * 4;
    float* msumB = (float*)w; w += (size_t)NP_ * 128 * 4;
    float* degC  = (float*)w; w += (size_t)NP_ * 4;   // click  dst deg (P)
    float* degQ  = (float*)w; w += (size_t)NP_ * 4;   // qres   dst deg (P)
    float* degRC = (float*)w; w += (size_t)NQ_ * 4;   // rclick dst deg (Q)
    float* degRQ = (float*)w; w += (size_t)NQ_ * 4;   // rqres  dst deg (Q)
    bf16* Wt     = (bf16*)w;  w += (size_t)12 * 16384 * 2;
    float* bsum  = (float*)w; w += 512 * 4;

    float* outQ = (float*)d_out;
    float* outP = outQ + (size_t)NQ_ * 128;

    // --- one-time prep ---
    cast_to_bf16<<<(NQ_ * 32 + 255) / 256, 256, 0, stream>>>(xq, xqb, NQ_ * 32);
    cast_to_bf16<<<(NP_ * 32 + 255) / 256, 256, 0, stream>>>(xp, xpb, NP_ * 32);
    prep_weights<<<768, 256, 0, stream>>>(Wself, Wneigh, Wt);
    prep_bias<<<2, 256, 0, stream>>>(bias, bsum);

    hipMemsetAsync(degC, 0, (size_t)NP_ * 4, stream);
    hipMemsetAsync(degQ, 0, (size_t)NP_ * 4, stream);
    hipMemsetAsync(degRC, 0, (size_t)NQ_ * 4, stream);
    hipMemsetAsync(degRQ, 0, (size_t)NQ_ * 4, stream);
    const int egrid = (NE_ + 255) / 256;
    deg_count<<<egrid, 256, 0, stream>>>(cdst, degC, NE_);
    deg_count<<<egrid, 256, 0, stream>>>(qdst, degQ, NE_);
    deg_count<<<egrid, 256, 0, stream>>>(rcdst, degRC, NE_);
    deg_count<<<egrid, 256, 0, stream>>>(rqdst, degRQ, NE_);

    const int sgrid = (NE_ + 3) / 4;

    for (int l = 0; l < 2; ++l) {
        const bf16* hQin = l ? hQ1 : xqb;
        const bf16* hPin = l ? hP1 : xpb;
        const bf16* WtP = Wt + (size_t)(l * 2 + 0) * 3 * 16384;
        const bf16* WtQ = Wt + (size_t)(l * 2 + 1) * 3 * 16384;
        const float* bP = bsum + (l * 2 + 0) * 128;
        const float* bQ = bsum + (l * 2 + 1) * 128;

        // --- P update: click + qres, sources are Q nodes ---
        hipMemsetAsync(msumA, 0, (size_t)NP_ * 128 * 4, stream);
        hipMemsetAsync(msumB, 0, (size_t)NP_ * 128 * 4, stream);
        scatter_add<<<sgrid, 256, 0, stream>>>(hQin, csrc, cdst, msumA, NE_);
        scatter_add<<<sgrid, 256, 0, stream>>>(hQin, qsrc, qdst, msumB, NE_);
        if (l == 0)
            sage_update<bf16><<<(NP_ + 63) / 64, 256, 0, stream>>>(hPin, msumA, degC, msumB, degQ,
                                                                   WtP, bP, hP1, NP_, 1);
        else
            sage_update<float><<<(NP_ + 63) / 64, 256, 0, stream>>>(hPin, msumA, degC, msumB, degQ,
                                                                    WtP, bP, outP, NP_, 0);

        // --- Q update: rclick + rqres, sources are P nodes ---
        hipMemsetAsync(msumA, 0, (size_t)NQ_ * 128 * 4, stream);
        hipMemsetAsync(msumB, 0, (size_t)NQ_ * 128 * 4, stream);
        scatter_add<<<sgrid, 256, 0, stream>>>(hPin, rcsrc, rcdst, msumA, NE_);
        scatter_add<<<sgrid, 256, 0, stream>>>(hPin, rqsrc, rqdst, msumB, NE_);
        if (l == 0)
            sage_update<bf16><<<(NQ_ + 63) / 64, 256, 0, stream>>>(hQin, msumA, degRC, msumB, degRQ,
                                                                   WtQ, bQ, hQ1, NQ_, 1);
        else
            sage_update<float><<<(NQ_ + 63) / 64, 256, 0, stream>>>(hQin, msumA, degRC, msumB, degRQ,
                                                                    WtQ, bQ, outQ, NQ_, 0);
    }
}

// Round 3
// 1114.592 us; speedup vs baseline: 3.5525x; 3.5525x over previous
//
#include <hip/hip_runtime.h>
#include <hip/hip_bf16.h>

typedef __hip_bfloat16 bf16;
typedef __attribute__((ext_vector_type(8))) short bfrag8;
typedef __attribute__((ext_vector_type(4))) float facc4;

#define NQ_ 100000
#define NP_ 200000
#define NE_ 500000

static __device__ __forceinline__ short f2bf_bits(float f) {
    bf16 h = __float2bfloat16(f);
    short r;
    __builtin_memcpy(&r, &h, 2);
    return r;
}

static __device__ __forceinline__ void store_val(bf16* p, float v) { *p = __float2bfloat16(v); }
static __device__ __forceinline__ void store_val(float* p, float v) { *p = v; }

// fp32 -> bf16 cast, 4 elems/thread
__global__ void cast_to_bf16(const float* __restrict__ x, bf16* __restrict__ y, int n4) {
    int i = blockIdx.x * blockDim.x + threadIdx.x;
    if (i >= n4) return;
    float4 v = reinterpret_cast<const float4*>(x)[i];
    short4 o;
    o.x = f2bf_bits(v.x);
    o.y = f2bf_bits(v.y);
    o.z = f2bf_bits(v.z);
    o.w = f2bf_bits(v.w);
    reinterpret_cast<short4*>(y)[i] = o;
}

// Combine + transpose weights (fp32 in, bf16 out): Wt[m][n*128+k], m = (l*2+t)*3+s
__global__ void prep_weights(const float* __restrict__ Wself, const float* __restrict__ Wneigh,
                             bf16* __restrict__ Wt) {
    int g = blockIdx.x * blockDim.x + threadIdx.x;
    if (g >= 12 * 16384) return;
    int m = g >> 14;
    int rem = g & 16383;
    int n = rem >> 7, k = rem & 127;
    int l = m / 6, t = (m / 3) % 2, s = m % 3;
    int rA = (t == 0) ? 0 : 1;
    int rB = (t == 0) ? 3 : 2;
    float v;
    if (s == 0) {
        v = Wself[((size_t)(l * 4 + rA) * 128 + k) * 128 + n]
          + Wself[((size_t)(l * 4 + rB) * 128 + k) * 128 + n];
    } else {
        int r = (s == 1) ? rA : rB;
        v = Wneigh[((size_t)(l * 4 + r) * 128 + k) * 128 + n];
    }
    Wt[(size_t)m * 16384 + n * 128 + k] = __float2bfloat16(v);
}

__global__ void prep_bias(const float* __restrict__ bias, float* __restrict__ bsum) {
    int g = blockIdx.x * blockDim.x + threadIdx.x;
    if (g >= 512) return;
    int l = g >> 8, t = (g >> 7) & 1, n = g & 127;
    int rA = (t == 0) ? 0 : 1;
    int rB = (t == 0) ? 3 : 2;
    bsum[g] = bias[(l * 4 + rA) * 128 + n] + bias[(l * 4 + rB) * 128 + n];
}

// ---------------- CSR build (counting sort by dst) ----------------

__global__ void deg_count(const int* __restrict__ dst, int* __restrict__ deg, int nE) {
    int e = blockIdx.x * blockDim.x + threadIdx.x;
    if (e < nE) atomicAdd(deg + dst[e], 1);
}

// pass1: per-block (1024 elems) exclusive scan -> offs, block total -> partials
__global__ void scan1(const int* __restrict__ deg, int* __restrict__ offs,
                      int* __restrict__ partials, int n) {
    __shared__ int sdata[256];
    int base = blockIdx.x * 1024;
    int t = threadIdx.x;
    int v[4]; int s = 0;
    for (int j = 0; j < 4; ++j) {
        int i = base + t * 4 + j;
        v[j] = (i < n) ? deg[i] : 0;
        s += v[j];
    }
    sdata[t] = s;
    __syncthreads();
    for (int d2 = 1; d2 < 256; d2 <<= 1) {
        int x = (t >= d2) ? sdata[t - d2] : 0;
        __syncthreads();
        sdata[t] += x;
        __syncthreads();
    }
    int excl = sdata[t] - s;
    if (t == 255) partials[blockIdx.x] = sdata[255];
    int run = excl;
    for (int j = 0; j < 4; ++j) {
        int i = base + t * 4 + j;
        if (i < n) offs[i] = run;
        run += v[j];
    }
}

// pass2: exclusive scan of partials (single block, nparts <= 256)
__global__ void scan2(int* __restrict__ partials, int nparts) {
    __shared__ int sdata[256];
    int t = threadIdx.x;
    int s = (t < nparts) ? partials[t] : 0;
    sdata[t] = s;
    __syncthreads();
    for (int d2 = 1; d2 < 256; d2 <<= 1) {
        int x = (t >= d2) ? sdata[t - d2] : 0;
        __syncthreads();
        sdata[t] += x;
        __syncthreads();
    }
    if (t < nparts) partials[t] = sdata[t] - s;
}

// pass3: add block offsets
__global__ void scan3(int* __restrict__ offs, const int* __restrict__ partials, int n) {
    int i = blockIdx.x * blockDim.x + threadIdx.x;
    if (i < n) offs[i] += partials[i >> 10];
}

// bucket[off[d] + cursor[d]++] = src[e]
__global__ void csr_fill(const int* __restrict__ src, const int* __restrict__ dst,
                         const int* __restrict__ off, int* __restrict__ cursor,
                         int* __restrict__ bucket, int nE) {
    int e = blockIdx.x * blockDim.x + threadIdx.x;
    if (e >= nE) return;
    int d = dst[e];
    int pos = atomicAdd(cursor + d, 1);
    bucket[off[d] + pos] = src[e];
}

// ---------------- gather-based mean aggregation ----------------
// one wave per dst node; lane handles feats 2*lane, 2*lane+1
__global__ void gather_mean(const bf16* __restrict__ h, const int* __restrict__ bucket,
                            const int* __restrict__ off, const int* __restrict__ deg,
                            bf16* __restrict__ mean, int ndst) {
    int d = blockIdx.x * 4 + (threadIdx.x >> 6);
    if (d >= ndst) return;
    int lane = threadIdx.x & 63;
    int beg = off[d], cnt = deg[d];
    float a0 = 0.0f, a1 = 0.0f;
    // lane-parallel index fetch + shfl broadcast (cnt <= 64 virtually always)
    int myidx = (lane < cnt) ? bucket[beg + lane] : 0;
    int c64 = (cnt < 64) ? cnt : 64;
    for (int i = 0; i < c64; ++i) {
        int s_ = __shfl(myidx, i);
        __hip_bfloat162 v = reinterpret_cast<const __hip_bfloat162*>(h + (size_t)s_ * 128)[lane];
        a0 += __low2float(v);
        a1 += __high2float(v);
    }
    for (int i = 64; i < cnt; ++i) {   // rare tail
        int s_ = bucket[beg + i];
        __hip_bfloat162 v = reinterpret_cast<const __hip_bfloat162*>(h + (size_t)s_ * 128)[lane];
        a0 += __low2float(v);
        a1 += __high2float(v);
    }
    float r = (cnt > 0) ? (1.0f / (float)cnt) : 0.0f;
    unsigned lo = (unsigned short)f2bf_bits(a0 * r);
    unsigned hi = (unsigned short)f2bf_bits(a1 * r);
    reinterpret_cast<unsigned*>(mean + (size_t)d * 128)[lane] = (hi << 16) | lo;
}

// ---------------- fused SAGE update (MFMA) ----------------
// out[i,:] = act( hdst[i,:]@W0 + mean1[i,:]@W1 + mean2[i,:]@W2 + bias )
template <typename OT>
__global__ __launch_bounds__(256, 2)
void sage_update(const bf16* __restrict__ hdst,
                 const bf16* __restrict__ mean1, const bf16* __restrict__ mean2,
                 const bf16* __restrict__ Wt3, const float* __restrict__ bsum,
                 OT* __restrict__ out, int nrows, int do_relu) {
    __shared__ short lA[64 * 136];   // A tile, stride 136 (272B: 16B-aligned, conflict-free b128)
    __shared__ short lW[128 * 136];  // W^T tile
    const int tid = threadIdx.x;
    const int wave = tid >> 6, lane = tid & 63;
    const int i16 = lane & 15, quad = lane >> 4;
    const int row0 = blockIdx.x * 64;

    const bf16* Asrc[3] = {hdst, mean1, mean2};

    facc4 acc[4][2];
    for (int nt = 0; nt < 2; ++nt) {
        float bv = bsum[wave * 32 + nt * 16 + i16];
        for (int mt = 0; mt < 4; ++mt) {
            facc4 a = {bv, bv, bv, bv};
            acc[mt][nt] = a;
        }
    }

    for (int s = 0; s < 3; ++s) {
        __syncthreads();
        // stage W_s^T
        {
            const int4* srcw = reinterpret_cast<const int4*>(Wt3 + (size_t)s * 16384);
            for (int j = 0; j < 8; ++j) {
                int c = j * 256 + tid;
                int n = c >> 4, k = (c & 15) * 8;
                *reinterpret_cast<int4*>(&lW[n * 136 + k]) = srcw[c];
            }
        }
        // stage A_s
        {
            const bf16* A = Asrc[s];
            for (int j = 0; j < 4; ++j) {
                int c = j * 256 + tid;
                int r = c >> 4, k = (c & 15) * 8;
                int grow = row0 + r;
                int4 v = {0, 0, 0, 0};
                if (grow < nrows)
                    v = reinterpret_cast<const int4*>(A)[((size_t)grow * 128 + k) >> 3];
                *reinterpret_cast<int4*>(&lA[r * 136 + k]) = v;
            }
        }
        __syncthreads();
        for (int k0 = 0; k0 < 128; k0 += 32) {
            bfrag8 a[4], b[2];
            for (int mt = 0; mt < 4; ++mt)
                a[mt] = *reinterpret_cast<const bfrag8*>(&lA[(mt * 16 + i16) * 136 + k0 + quad * 8]);
            for (int nt = 0; nt < 2; ++nt)
                b[nt] = *reinterpret_cast<const bfrag8*>(&lW[(wave * 32 + nt * 16 + i16) * 136 + k0 + quad * 8]);
            for (int mt = 0; mt < 4; ++mt)
                for (int nt = 0; nt < 2; ++nt)
                    acc[mt][nt] = __builtin_amdgcn_mfma_f32_16x16x32_bf16(a[mt], b[nt], acc[mt][nt], 0, 0, 0);
        }
    }

    for (int mt = 0; mt < 4; ++mt) {
        for (int nt = 0; nt < 2; ++nt) {
            int n = wave * 32 + nt * 16 + i16;
            for (int r = 0; r < 4; ++r) {
                int m = mt * 16 + quad * 4 + r;
                int grow = row0 + m;
                if (grow < nrows) {
                    float v = acc[mt][nt][r];
                    if (do_relu) v = fmaxf(v, 0.0f);
                    store_val(out + (size_t)grow * 128 + n, v);
                }
            }
        }
    }
}

// ---------------- launch ----------------

static void build_csr(const int* dst, int* deg, int* off, int* cursor, int* bucket,
                      int* partials, const int* src, int ndst, hipStream_t stream) {
    hipMemsetAsync(deg, 0, (size_t)ndst * 4, stream);
    hipMemsetAsync(cursor, 0, (size_t)ndst * 4, stream);
    deg_count<<<(NE_ + 255) / 256, 256, 0, stream>>>(dst, deg, NE_);
    int nparts = (ndst + 1023) / 1024;
    scan1<<<nparts, 256, 0, stream>>>(deg, off, partials, ndst);
    scan2<<<1, 256, 0, stream>>>(partials, nparts);
    scan3<<<(ndst + 255) / 256, 256, 0, stream>>>(off, partials, ndst);
    csr_fill<<<(NE_ + 255) / 256, 256, 0, stream>>>(src, dst, off, cursor, bucket, NE_);
}

extern "C" void kernel_launch(void* const* d_in, const int* in_sizes, int n_in,
                              void* d_out, int out_size, void* d_ws, size_t ws_size,
                              hipStream_t stream) {
    const float* xq     = (const float*)d_in[0];
    const float* xp     = (const float*)d_in[1];
    const float* Wself  = (const float*)d_in[2];
    const float* Wneigh = (const float*)d_in[3];
    const float* bias   = (const float*)d_in[4];
    const int* csrc  = (const int*)d_in[5];
    const int* cdst  = (const int*)d_in[6];
    const int* qsrc  = (const int*)d_in[7];
    const int* qdst  = (const int*)d_in[8];
    const int* rcsrc = (const int*)d_in[9];
    const int* rcdst = (const int*)d_in[10];
    const int* rqsrc = (const int*)d_in[11];
    const int* rqdst = (const int*)d_in[12];

    char* w = (char*)d_ws;
    bf16* xqb    = (bf16*)w;  w += (size_t)NQ_ * 128 * 2;
    bf16* xpb    = (bf16*)w;  w += (size_t)NP_ * 128 * 2;
    bf16* hQ1    = (bf16*)w;  w += (size_t)NQ_ * 128 * 2;
    bf16* hP1    = (bf16*)w;  w += (size_t)NP_ * 128 * 2;
    bf16* meanA  = (bf16*)w;  w += (size_t)NP_ * 128 * 2;
    bf16* meanB  = (bf16*)w;  w += (size_t)NP_ * 128 * 2;
    bf16* Wt     = (bf16*)w;  w += (size_t)12 * 16384 * 2;
    float* bsum  = (float*)w; w += 512 * 4;
    // CSR per relation: deg, off, cursor (ndst each) + bucket (NE)
    int* degC  = (int*)w; w += (size_t)NP_ * 4;
    int* offC  = (int*)w; w += (size_t)NP_ * 4;
    int* curC  = (int*)w; w += (size_t)NP_ * 4;
    int* bukC  = (int*)w; w += (size_t)NE_ * 4;
    int* degQr = (int*)w; w += (size_t)NP_ * 4;
    int* offQr = (int*)w; w += (size_t)NP_ * 4;
    int* curQr = (int*)w; w += (size_t)NP_ * 4;
    int* bukQr = (int*)w; w += (size_t)NE_ * 4;
    int* degRC = (int*)w; w += (size_t)NQ_ * 4;
    int* offRC = (int*)w; w += (size_t)NQ_ * 4;
    int* curRC = (int*)w; w += (size_t)NQ_ * 4;
    int* bukRC = (int*)w; w += (size_t)NE_ * 4;
    int* degRQ = (int*)w; w += (size_t)NQ_ * 4;
    int* offRQ = (int*)w; w += (size_t)NQ_ * 4;
    int* curRQ = (int*)w; w += (size_t)NQ_ * 4;
    int* bukRQ = (int*)w; w += (size_t)NE_ * 4;
    int* partials = (int*)w; w += 256 * 4;

    float* outQ = (float*)d_out;
    float* outP = outQ + (size_t)NQ_ * 128;

    // --- one-time prep ---
    cast_to_bf16<<<(NQ_ * 32 + 255) / 256, 256, 0, stream>>>(xq, xqb, NQ_ * 32);
    cast_to_bf16<<<(NP_ * 32 + 255) / 256, 256, 0, stream>>>(xp, xpb, NP_ * 32);
    prep_weights<<<768, 256, 0, stream>>>(Wself, Wneigh, Wt);
    prep_bias<<<2, 256, 0, stream>>>(bias, bsum);

    build_csr(cdst,  degC,  offC,  curC,  bukC,  partials, csrc,  NP_, stream);
    build_csr(qdst,  degQr, offQr, curQr, bukQr, partials, qsrc,  NP_, stream);
    build_csr(rcdst, degRC, offRC, curRC, bukRC, partials, rcsrc, NQ_, stream);
    build_csr(rqdst, degRQ, offRQ, curRQ, bukRQ, partials, rqsrc, NQ_, stream);

    for (int l = 0; l < 2; ++l) {
        const bf16* hQin = l ? hQ1 : xqb;
        const bf16* hPin = l ? hP1 : xpb;
        const bf16* WtP = Wt + (size_t)(l * 2 + 0) * 3 * 16384;
        const bf16* WtQ = Wt + (size_t)(l * 2 + 1) * 3 * 16384;
        const float* bP = bsum + (l * 2 + 0) * 128;
        const float* bQ = bsum + (l * 2 + 1) * 128;

        // --- P update: click + qres (sources = Q nodes) ---
        gather_mean<<<(NP_ + 3) / 4, 256, 0, stream>>>(hQin, bukC,  offC,  degC,  meanA, NP_);
        gather_mean<<<(NP_ + 3) / 4, 256, 0, stream>>>(hQin, bukQr, offQr, degQr, meanB, NP_);
        if (l == 0)
            sage_update<bf16><<<(NP_ + 63) / 64, 256, 0, stream>>>(hPin, meanA, meanB, WtP, bP, hP1, NP_, 1);
        else
            sage_update<float><<<(NP_ + 63) / 64, 256, 0, stream>>>(hPin, meanA, meanB, WtP, bP, outP, NP_, 0);

        // --- Q update: rclick + rqres (sources = P nodes) ---
        gather_mean<<<(NQ_ + 3) / 4, 256, 0, stream>>>(hPin, bukRC, offRC, degRC, meanA, NQ_);
        gather_mean<<<(NQ_ + 3) / 4, 256, 0, stream>>>(hPin, bukRQ, offRQ, degRQ, meanB, NQ_);
        if (l == 0)
            sage_update<bf16><<<(NQ_ + 63) / 64, 256, 0, stream>>>(hQin, meanA, meanB, WtQ, bQ, hQ1, NQ_, 1);
        else
            sage_update<float><<<(NQ_ + 63) / 64, 256, 0, stream>>>(hQin, meanA, meanB, WtQ, bQ, outQ, NQ_, 0);
    }
}